// Round 3
// baseline (191.768 us; speedup 1.0000x reference)
//
#include <hip/hip_runtime.h>
#include <stdint.h>

#define HN 16
#define DH 64
#define MF 64
#define CHK 128
#define NCH 32
#define TSEQ 4096
#define CIN 1024
#define C3 3072

typedef __attribute__((ext_vector_type(8))) short bf16x8;
typedef __attribute__((ext_vector_type(4))) float f32x4;

__device__ __forceinline__ unsigned short f2b(float f){
  union{float f;uint32_t u;} v; v.f=f;
  return (unsigned short)((v.u + 0x7fffu + ((v.u>>16)&1u))>>16);
}

#define MFMA(a,b,c) __builtin_amdgcn_mfma_f32_16x16x32_bf16(a,b,c,0,0,0)

typedef __attribute__((address_space(1))) void gbl_t;
typedef __attribute__((address_space(3))) void lds_t;
__device__ __forceinline__ void gload_lds16(const void* g, void* l){
  __builtin_amdgcn_global_load_lds((const gbl_t*)g, (lds_t*)l, 16, 0, 0);
}

// ---------------- conversion kernels ----------------
__global__ __launch_bounds__(256) void cvt_kernel(const float* __restrict__ src,
                                                  unsigned short* __restrict__ dst, int n4){
  int i = blockIdx.x*256 + threadIdx.x;
  if (i >= n4) return;
  float4 v = ((const float4*)src)[i];
  uint64_t pk = (uint64_t)f2b(v.x) | ((uint64_t)f2b(v.y)<<16)
              | ((uint64_t)f2b(v.z)<<32) | ((uint64_t)f2b(v.w)<<48);
  *(uint64_t*)(dst + (size_t)i*4) = pk;
}

// proj (H,D,M) f32 -> projT (H,M,D) bf16
__global__ __launch_bounds__(256) void projt_kernel(const float* __restrict__ proj,
                                                    unsigned short* __restrict__ projT){
  int i = blockIdx.x*256 + threadIdx.x;
  if (i >= HN*DH*MF) return;
  int h = i>>12, r = i&4095, d = r>>6, m = r&63;
  projT[(h<<12) + (m<<6) + d] = f2b(proj[i]);
}

// ================= 256x256 8-phase GEMM: C[M][N] = A[M][K] * Bt[N][K]^T + bias =================
// 8 waves (2Mx4N), per-wave 128x64 out. BK=64, 2 K-tiles/iteration, 8 phases.
// LDS [256][64] bf16 per buffer per matrix (32768 B per buffer -> buf<<15).
// 16B-seg XOR swizzle: seg_stored = seg_true ^ (row&7); global_load_lds writes
// linearly, the global source column carries the inverse permutation.
// Counted vmcnt(4) at phases p3/p7 only (never drain to 0 in the loop).
template<int OUT_BF16, int KK>
__global__ __launch_bounds__(512, 2) void gemm8p_kernel(
    const unsigned short* __restrict__ A, const unsigned short* __restrict__ Bt,
    const float* __restrict__ bias, void* __restrict__ Cout,
    int Nn, int nbN)
{
  static_assert(KK % 128 == 0, "KK multiple of 128");
  constexpr int NT = KK / 64;          // K-tiles
  constexpr int NI = NT / 2;           // iterations
  static_assert((NT & (NT-1)) == 0, "NT pow2 for wrap");

  __shared__ unsigned short sA[2*256*64];
  __shared__ unsigned short sB[2*256*64];

  int tid = threadIdx.x;
  int w = tid>>6, l = tid&63, g = l>>4, r16 = l&15;
  int wr = w>>2, wc = w&3;

  // bijective XCD swizzle (gridDim.x % 8 == 0 for both call sites)
  int nwg = gridDim.x;
  int qq = nwg>>3;
  int wgid = (blockIdx.x & 7)*qq + (blockIdx.x>>3);
  int brow = (wgid / nbN)<<8;
  int bcol = (wgid % nbN)<<8;

  int rofs = tid>>3;                       // row within 64-row issue
  int cofs = ((tid&7) ^ ((tid>>3)&7))<<3;  // inverse-swizzled source column (elems)

  const unsigned short* Ab = A + (size_t)brow*KK;
  const unsigned short* Bb = Bt + (size_t)bcol*KK;
  char* sAc = (char*)sA;
  char* sBc = (char*)sB;

  f32x4 acc[8][4];
  #pragma unroll
  for (int m=0;m<8;m++)
    #pragma unroll
    for (int n=0;n<4;n++) acc[m][n] = (f32x4){0.f,0.f,0.f,0.f};

  // stage one 128-row half (2 x global_load_lds of 64 rows each)
  auto stgA = [&](int buf, int half, int kt){
    int r0 = half<<7;
    const unsigned short* gp = Ab + (size_t)(r0 + rofs)*KK + (kt<<6) + cofs;
    char* lp = sAc + (buf<<15) + (r0<<7) + (tid<<4);
    gload_lds16(gp, lp);
    gload_lds16(gp + (size_t)64*KK, lp + 64*128);
  };
  auto stgB = [&](int buf, int half, int kt){
    int r0 = half<<7;
    const unsigned short* gp = Bb + (size_t)(r0 + rofs)*KK + (kt<<6) + cofs;
    char* lp = sBc + (buf<<15) + (r0<<7) + (tid<<4);
    gload_lds16(gp, lp);
    gload_lds16(gp + (size_t)64*KK, lp + 64*128);
  };

#define PHASE(BUF, MH, NH, STAGES, GUARD) do{                                      \
    bf16x8 af[4][2], bfv[2][2];                                                    \
    const char* sab = sAc + ((BUF)<<15);                                           \
    const char* sbb = sBc + ((BUF)<<15);                                           \
    _Pragma("unroll")                                                              \
    for (int mf_=0; mf_<4; mf_++){                                                 \
      int row = (MH)*128 + wr*64 + mf_*16 + r16;                                   \
      _Pragma("unroll")                                                            \
      for (int ks_=0; ks_<2; ks_++)                                                \
        af[mf_][ks_] = *(const bf16x8*)(sab + row*128 + (((ks_*4+g)^(r16&7))<<4)); \
    }                                                                              \
    _Pragma("unroll")                                                              \
    for (int nf_=0; nf_<2; nf_++){                                                 \
      int row = (NH)*128 + wc*32 + nf_*16 + r16;                                   \
      _Pragma("unroll")                                                            \
      for (int ks_=0; ks_<2; ks_++)                                                \
        bfv[nf_][ks_] = *(const bf16x8*)(sbb + row*128 + (((ks_*4+g)^(r16&7))<<4));\
    }                                                                              \
    STAGES;                                                                        \
    GUARD;                                                                         \
    __builtin_amdgcn_s_barrier();                                                  \
    __builtin_amdgcn_sched_barrier(0);                                             \
    __builtin_amdgcn_s_setprio(1);                                                 \
    _Pragma("unroll")                                                              \
    for (int mf_=0; mf_<4; mf_++)                                                  \
      _Pragma("unroll")                                                            \
      for (int nf_=0; nf_<2; nf_++)                                                \
        _Pragma("unroll")                                                          \
        for (int ks_=0; ks_<2; ks_++)                                              \
          acc[(MH)*4+mf_][(NH)*2+nf_] =                                            \
            MFMA(af[mf_][ks_], bfv[nf_][ks_], acc[(MH)*4+mf_][(NH)*2+nf_]);        \
    __builtin_amdgcn_s_setprio(0);                                                 \
    __builtin_amdgcn_sched_barrier(0);                                             \
    __builtin_amdgcn_s_barrier();                                                  \
    asm volatile("" ::: "memory");                                                 \
  }while(0)

#define VM4 asm volatile("s_waitcnt vmcnt(4)" ::: "memory")

  // prologue: tile0 full -> buf0, tile1 low halves -> buf1
  stgA(0,0,0); stgA(0,1,0); stgB(0,0,0); stgB(0,1,0);
  stgA(1,0,1); stgB(1,0,1);
  VM4;
  __builtin_amdgcn_s_barrier();
  asm volatile("" ::: "memory");

  for (int it=0; it<NI; ++it){
    int t1 = 2*it+1;
    int t2 = (2*it+2) & (NT-1);
    int t3 = (2*it+3) & (NT-1);
    // K-tile 2it in buf0
    PHASE(0, 0,0, { stgA(1,1,t1); stgB(1,1,t1); }, {});
    PHASE(0, 0,1, {}, {});
    PHASE(0, 1,0, { stgA(0,0,t2); }, {});
    PHASE(0, 1,1, { stgB(0,0,t2); }, VM4);
    // K-tile 2it+1 in buf1
    PHASE(1, 0,0, { stgA(0,1,t2); stgB(0,1,t2); }, {});
    PHASE(1, 0,1, {}, {});
    PHASE(1, 1,0, { stgA(1,0,t3); }, {});
    PHASE(1, 1,1, { stgB(1,0,t3); }, VM4);
  }
#undef PHASE
#undef VM4

  // epilogue
  #pragma unroll
  for (int n=0;n<4;n++){
    int colg = bcol + (n>>1)*128 + wc*32 + (n&1)*16 + r16;
    float bv = bias[colg];
    #pragma unroll
    for (int m=0;m<8;m++){
      int rowg = brow + (m>>2)*128 + wr*64 + (m&3)*16 + g*4;
      #pragma unroll
      for (int j=0;j<4;j++){
        float v = acc[m][n][j] + bv;
        if (OUT_BF16) ((unsigned short*)Cout)[(size_t)(rowg+j)*Nn + colg] = f2b(v);
        else          ((float*)Cout)[(size_t)(rowg+j)*Nn + colg] = v;
      }
    }
  }
}

// ---------------- per-chunk stats: S = kp^T v, ssum = sum_t kp ----------------
__global__ __launch_bounds__(256) void chunk_stats_kernel(
    const unsigned short* __restrict__ qkvb,
    const unsigned short* __restrict__ projT,
    float* __restrict__ Sbuf, float* __restrict__ ssum)
{
  __shared__ unsigned short s_pT[64*64];    // [m][d]  rows 128B, swz (m&7)<<4
  __shared__ unsigned short s_kpT[64*128];  // [m][t]  rows 256B, swz (m&15)<<4
  __shared__ unsigned short s_vT[64*128];   // [d][t]  rows 256B, swz (d&15)<<4
  __shared__ float s_part[256];

  int bid = blockIdx.x;
  int ch = bid&31, h = (bid>>5)&15, b = bid>>9;
  int tid = threadIdx.x, w = tid>>6, l = tid&63, g = l>>4, r16 = l&15;
  int rowbase = b*TSEQ + ch*CHK;
  const unsigned short* kg = qkvb + (size_t)rowbase*C3 + CIN   + h*DH;
  const unsigned short* vg = qkvb + (size_t)rowbase*C3 + 2*CIN + h*DH;

  {
    const unsigned short* p = projT + (h<<12);
    for (int i = tid; i < 4096; i += 256){
      int m = i>>6, d = i&63;
      *(unsigned short*)((char*)s_pT + m*128 + (((d*2) ^ ((m&7)<<4)))) = p[i];
    }
  }
  for (int i = tid; i < 1024; i += 256){
    int t = i>>3, d0 = (i&7)<<3;
    bf16x8 vv = *(const bf16x8*)(vg + (size_t)t*C3 + d0);
    #pragma unroll
    for (int j=0;j<8;j++){
      int d = d0+j;
      *(unsigned short*)((char*)s_vT + d*256 + (((t*2) ^ ((d&15)<<4)))) = (unsigned short)vv[j];
    }
  }
  __syncthreads();

  // kp = relu(k @ projT^T): M=t(128 rows, 32/wave), N=m(64), K=d(64)
  f32x4 kacc[2][4];
  #pragma unroll
  for (int tr=0;tr<2;tr++)
    #pragma unroll
    for (int nc=0;nc<4;nc++) kacc[tr][nc] = (f32x4){0.f,0.f,0.f,0.f};
  #pragma unroll
  for (int ks=0; ks<2; ks++){
    bf16x8 a[2];
    #pragma unroll
    for (int tr=0;tr<2;tr++){
      int t = w*32 + tr*16 + r16;
      a[tr] = *(const bf16x8*)(kg + (size_t)t*C3 + ks*32 + g*8);
    }
    #pragma unroll
    for (int nc=0;nc<4;nc++){
      int m = nc*16 + r16;
      bf16x8 bb = *(const bf16x8*)((const char*)s_pT + m*128 + (((ks*64 + g*16) ^ ((m&7)<<4))));
      #pragma unroll
      for (int tr=0;tr<2;tr++)
        kacc[tr][nc] = MFMA(a[tr], bb, kacc[tr][nc]);
    }
  }
  #pragma unroll
  for (int nc=0;nc<4;nc++){
    float v = 0.f;
    #pragma unroll
    for (int tr=0;tr<2;tr++)
      #pragma unroll
      for (int j=0;j<4;j++){
        float x = kacc[tr][nc][j]; x = x>0.f?x:0.f;
        v += x;
        int t = w*32 + tr*16 + g*4 + j;
        int m = nc*16 + r16;
        *(unsigned short*)((char*)s_kpT + m*256 + (((t*2) ^ ((m&15)<<4)))) = f2b(x);
      }
    v += __shfl_xor(v,16); v += __shfl_xor(v,32);
    if (g==0) s_part[w*64 + nc*16 + r16] = v;
  }
  __syncthreads();

  // S[m][d] = sum_t kp[t][m] v[t][d]: A=s_kpT [m][t], B=s_vT [d][t], K=t(128)
  f32x4 sacc[4];
  #pragma unroll
  for (int dc=0;dc<4;dc++) sacc[dc] = (f32x4){0.f,0.f,0.f,0.f};
  int mrow = w*16 + r16;
  #pragma unroll
  for (int ks=0; ks<4; ks++){
    bf16x8 a = *(const bf16x8*)((const char*)s_kpT + mrow*256 + (((ks*64 + g*16) ^ ((mrow&15)<<4))));
    #pragma unroll
    for (int dc=0; dc<4; dc++){
      int d = dc*16 + r16;
      bf16x8 bb = *(const bf16x8*)((const char*)s_vT + d*256 + (((ks*64 + g*16) ^ ((d&15)<<4))));
      sacc[dc] = MFMA(a, bb, sacc[dc]);
    }
  }
  float* So = Sbuf + ((size_t)((b*HN + h)*NCH + ch))*4096;
  #pragma unroll
  for (int dc=0; dc<4; dc++)
    #pragma unroll
    for (int j=0;j<4;j++)
      So[(w*16 + g*4 + j)*64 + dc*16 + r16] = sacc[dc][j];
  if (tid < 64){
    float v = s_part[tid] + s_part[64+tid] + s_part[128+tid] + s_part[192+tid];
    ssum[((size_t)((b*HN + h)*NCH + ch))*64 + tid] = v;
  }
}

// ---------------- exclusive prefix over chunks ----------------
__global__ __launch_bounds__(256) void scan_kernel(
  const float* __restrict__ Sbuf, const float* __restrict__ ssum,
  float* __restrict__ kvstate, float* __restrict__ kstate)
{
  int bh = blockIdx.x, tid = threadIdx.x;
  const float4* Sp = (const float4*)(Sbuf + (size_t)bh*NCH*4096);
  float4* kvp = (float4*)(kvstate + (size_t)bh*NCH*4096);
  float4 acc[4];
  #pragma unroll
  for (int q=0;q<4;q++) acc[q] = make_float4(0.f,0.f,0.f,0.f);
  for (int c2=0; c2<NCH; c2++){
    #pragma unroll
    for (int q=0;q<4;q++){
      int idx = c2*1024 + q*256 + tid;
      float4 s = Sp[idx];
      kvp[idx] = acc[q];
      acc[q].x += s.x; acc[q].y += s.y; acc[q].z += s.z; acc[q].w += s.w;
    }
  }
  if (tid < 64){
    float a = 0.f;
    const float* sp = ssum + (size_t)bh*NCH*64;
    float* kp2 = kstate + (size_t)bh*NCH*64;
    for (int c2=0;c2<NCH;c2++){ kp2[c2*64+tid] = a; a += sp[c2*64+tid]; }
  }
}

// ---------------- per-chunk output ----------------
__global__ __launch_bounds__(256) void chunk_out_kernel(
    const unsigned short* __restrict__ qkvb,
    const unsigned short* __restrict__ projT,
    const float* __restrict__ kvstate,
    const float* __restrict__ kstate,
    unsigned short* __restrict__ attnb)
{
  __shared__ unsigned short s_qp[128*64];   // [t][m] rows 128B, swz (t&7)<<4
  __shared__ unsigned short s_kp[128*64];   // [s][m] rows 128B, swz (s&7)<<4
  __shared__ unsigned short s_vT[64*128];   // [d][t] rows 256B, swz (d&15)<<4
  __shared__ unsigned short s_pa[64*64];    // projT [m][d] swz (m&7)<<4, then aw_sb [t][32] swz (t&3)<<4

  int bid = blockIdx.x;
  int ch = bid&31, h=(bid>>5)&15, b=bid>>9;
  int tid=threadIdx.x, w=tid>>6, l=tid&63, g=l>>4, r16=l&15;
  int rowbase = b*TSEQ + ch*CHK;
  const unsigned short* qg = qkvb + (size_t)rowbase*C3 + h*DH;
  const unsigned short* kg = qg + CIN;
  const unsigned short* vg = qg + 2*CIN;
  const float* kvg = kvstate + ((size_t)((b*HN+h)*NCH + ch))*4096;
  const float* ksg = kstate  + ((size_t)((b*HN+h)*NCH + ch))*64;

  {
    const unsigned short* p = projT + (h<<12);
    for (int i = tid; i < 4096; i += 256){
      int m = i>>6, d = i&63;
      *(unsigned short*)((char*)s_pa + m*128 + (((d*2) ^ ((m&7)<<4)))) = p[i];
    }
  }
  for (int i = tid; i < 1024; i += 256){
    int t = i>>3, d0 = (i&7)<<3;
    bf16x8 vv = *(const bf16x8*)(vg + (size_t)t*C3 + d0);
    #pragma unroll
    for (int j=0;j<8;j++){
      int d = d0+j;
      *(unsigned short*)((char*)s_vT + d*256 + (((t*2) ^ ((d&15)<<4)))) = (unsigned short)vv[j];
    }
  }
  __syncthreads();

  // qp = relu(q @ projT^T)
  f32x4 qacc[2][4];
  #pragma unroll
  for (int tr=0;tr<2;tr++)
    #pragma unroll
    for (int nc=0;nc<4;nc++) qacc[tr][nc] = (f32x4){0.f,0.f,0.f,0.f};
  #pragma unroll
  for (int ks=0; ks<2; ks++){
    bf16x8 a[2];
    #pragma unroll
    for (int tr=0;tr<2;tr++){
      int t = w*32 + tr*16 + r16;
      a[tr] = *(const bf16x8*)(qg + (size_t)t*C3 + ks*32 + g*8);
    }
    #pragma unroll
    for (int nc=0;nc<4;nc++){
      int m = nc*16 + r16;
      bf16x8 bb = *(const bf16x8*)((const char*)s_pa + m*128 + (((ks*64 + g*16) ^ ((m&7)<<4))));
      #pragma unroll
      for (int tr=0;tr<2;tr++)
        qacc[tr][nc] = MFMA(a[tr], bb, qacc[tr][nc]);
    }
  }
  // norm_hist partials + write qp
  float nh[2][4];
  #pragma unroll
  for (int tr=0;tr<2;tr++)
    #pragma unroll
    for (int j=0;j<4;j++) nh[tr][j] = 0.f;
  #pragma unroll
  for (int nc=0;nc<4;nc++){
    float ksv = ksg[nc*16 + r16];
    #pragma unroll
    for (int tr=0;tr<2;tr++)
      #pragma unroll
      for (int j=0;j<4;j++){
        float x = qacc[tr][nc][j]; x = x>0.f?x:0.f;
        nh[tr][j] += x*ksv;
        int t = w*32 + tr*16 + g*4 + j;
        int m = nc*16 + r16;
        *(unsigned short*)((char*)s_qp + t*128 + (((m*2) ^ ((t&7)<<4)))) = f2b(x);
      }
  }
  // kp = relu(k @ projT^T)
  f32x4 kacc[2][4];
  #pragma unroll
  for (int tr=0;tr<2;tr++)
    #pragma unroll
    for (int nc=0;nc<4;nc++) kacc[tr][nc] = (f32x4){0.f,0.f,0.f,0.f};
  #pragma unroll
  for (int ks=0; ks<2; ks++){
    bf16x8 a[2];
    #pragma unroll
    for (int tr=0;tr<2;tr++){
      int t = w*32 + tr*16 + r16;
      a[tr] = *(const bf16x8*)(kg + (size_t)t*C3 + ks*32 + g*8);
    }
    #pragma unroll
    for (int nc=0;nc<4;nc++){
      int m = nc*16 + r16;
      bf16x8 bb = *(const bf16x8*)((const char*)s_pa + m*128 + (((ks*64 + g*16) ^ ((m&7)<<4))));
      #pragma unroll
      for (int tr=0;tr<2;tr++)
        kacc[tr][nc] = MFMA(a[tr], bb, kacc[tr][nc]);
    }
  }
  #pragma unroll
  for (int nc=0;nc<4;nc++)
    #pragma unroll
    for (int tr=0;tr<2;tr++)
      #pragma unroll
      for (int j=0;j<4;j++){
        float x = kacc[tr][nc][j]; x = x>0.f?x:0.f;
        int t = w*32 + tr*16 + g*4 + j;
        int m = nc*16 + r16;
        *(unsigned short*)((char*)s_kp + t*128 + (((m*2) ^ ((t&7)<<4)))) = f2b(x);
      }
  __syncthreads();   // qp/kp ready; projT no longer needed

  f32x4 ctx[2][4];
  float ni[2][4];
  #pragma unroll
  for (int tr=0;tr<2;tr++){
    #pragma unroll
    for (int dc=0;dc<4;dc++) ctx[tr][dc] = (f32x4){0.f,0.f,0.f,0.f};
    #pragma unroll
    for (int j=0;j<4;j++) ni[tr][j] = 0.f;
  }

  // streamed aw (128x32 per block) + ctx_intra
  for (int sb=0; sb<4; sb++){
    f32x4 aw[2][2];
    #pragma unroll
    for (int tr=0;tr<2;tr++)
      #pragma unroll
      for (int sc=0;sc<2;sc++) aw[tr][sc] = (f32x4){0.f,0.f,0.f,0.f};
    #pragma unroll
    for (int ks=0; ks<2; ks++){
      bf16x8 a[2];
      #pragma unroll
      for (int tr=0;tr<2;tr++){
        int t = w*32 + tr*16 + r16;
        a[tr] = *(const bf16x8*)((const char*)s_qp + t*128 + (((ks*64 + g*16) ^ ((t&7)<<4))));
      }
      #pragma unroll
      for (int sc=0;sc<2;sc++){
        int s = sb*32 + sc*16 + r16;
        bf16x8 bb = *(const bf16x8*)((const char*)s_kp + s*128 + (((ks*64 + g*16) ^ ((s&7)<<4))));
        #pragma unroll
        for (int tr=0;tr<2;tr++)
          aw[tr][sc] = MFMA(a[tr], bb, aw[tr][sc]);
      }
    }
    #pragma unroll
    for (int tr=0;tr<2;tr++)
      #pragma unroll
      for (int sc=0;sc<2;sc++)
        #pragma unroll
        for (int j=0;j<4;j++){
          int t = w*32 + tr*16 + g*4 + j;
          int s = sb*32 + sc*16 + r16;
          float x = (s<=t)? aw[tr][sc][j] : 0.f;
          ni[tr][j] += x;
          int sl = sc*16 + r16;
          *(unsigned short*)((char*)s_pa + t*64 + (((sl*2) ^ ((t&3)<<4)))) = f2b(x);
        }
    __syncthreads();
    #pragma unroll
    for (int tr=0;tr<2;tr++){
      int t = w*32 + tr*16 + r16;
      bf16x8 a2 = *(const bf16x8*)((const char*)s_pa + t*64 + (((g*16) ^ ((t&3)<<4))));
      #pragma unroll
      for (int dc=0;dc<4;dc++){
        int d = dc*16 + r16;
        bf16x8 bb = *(const bf16x8*)((const char*)s_vT + d*256 + (((sb*64 + g*16) ^ ((d&15)<<4))));
        ctx[tr][dc] = MFMA(a2, bb, ctx[tr][dc]);
      }
    }
    __syncthreads();
  }

  // ctx_hist += qp @ kv_state  (B[k=m][n=d] = kvstate[m][d], scalar f32 loads)
  #pragma unroll
  for (int ks=0; ks<2; ks++){
    bf16x8 a[2];
    #pragma unroll
    for (int tr=0;tr<2;tr++){
      int t = w*32 + tr*16 + r16;
      a[tr] = *(const bf16x8*)((const char*)s_qp + t*128 + (((ks*64 + g*16) ^ ((t&7)<<4))));
    }
    #pragma unroll
    for (int dc=0;dc<4;dc++){
      bf16x8 bb;
      #pragma unroll
      for (int i=0;i<8;i++)
        bb[i] = (short)f2b(kvg[(ks*32 + g*8 + i)*64 + dc*16 + r16]);
      #pragma unroll
      for (int tr=0;tr<2;tr++)
        ctx[tr][dc] = MFMA(a[tr], bb, ctx[tr][dc]);
    }
  }

  // norms: butterfly over the 16-lane group (sums s-mod-16 / m-mod-16 partials)
  float nrm[2][4];
  #pragma unroll
  for (int tr=0;tr<2;tr++)
    #pragma unroll
    for (int j=0;j<4;j++){
      float v = nh[tr][j] + ni[tr][j];
      v += __shfl_xor(v,1); v += __shfl_xor(v,2);
      v += __shfl_xor(v,4); v += __shfl_xor(v,8);
      nrm[tr][j] = v + 1e-6f;
    }

  #pragma unroll
  for (int tr=0;tr<2;tr++)
    #pragma unroll
    for (int dc=0;dc<4;dc++)
      #pragma unroll
      for (int j=0;j<4;j++){
        int t = w*32 + tr*16 + g*4 + j;
        int d = dc*16 + r16;
        attnb[(size_t)(rowbase + t)*CIN + h*DH + d] = f2b(ctx[tr][dc][j] / nrm[tr][j]);
      }
}

// ---------------- launch ----------------
extern "C" void kernel_launch(void* const* d_in, const int* in_sizes, int n_in,
                              void* d_out, int out_size, void* d_ws, size_t ws_size,
                              hipStream_t stream)
{
  const float* x    = (const float*)d_in[0];
  const float* Wqkv = (const float*)d_in[1];
  const float* bqkv = (const float*)d_in[2];
  const float* Wout = (const float*)d_in[3];
  const float* bout = (const float*)d_in[4];
  const float* proj = (const float*)d_in[5];

  char* ws = (char*)d_ws;
  unsigned short* xb     = (unsigned short*)(ws + 0);         // 16 MB (reused as attnb)
  unsigned short* attnb  = (unsigned short*)(ws + 0);
  unsigned short* wqkvb  = (unsigned short*)(ws + 16777216);  // 6 MB (reused as ssum/kstate)
  float*          ssum   = (float*)(ws + 16777216);
  float*          kstate = (float*)(ws + 17039360);
  unsigned short* qkvb   = (unsigned short*)(ws + 23068672);  // 50 MB
  unsigned short* woutb  = (unsigned short*)(ws + 73400320);  // 2 MB
  unsigned short* projTb = (unsigned short*)(ws + 75497472);  // 128 KB
  float*          Sbuf   = (float*)(ws + 75628544);           // 16 MB
  float*          kvstate= (float*)(ws + 92405760);           // 16 MB

  cvt_kernel<<<8192, 256, 0, stream>>>(x, xb, 2097152);
  cvt_kernel<<<3072, 256, 0, stream>>>(Wqkv, wqkvb, 786432);
  cvt_kernel<<<1024, 256, 0, stream>>>(Wout, woutb, 262144);
  projt_kernel<<<256, 256, 0, stream>>>(proj, projTb);

  // QKV GEMM: M=8192, N=3072, K=1024 -> 32x12 = 384 blocks (384%8==0)
  gemm8p_kernel<1,1024><<<384, 512, 0, stream>>>(xb, wqkvb, bqkv, qkvb, 3072, 12);

  chunk_stats_kernel<<<1024, 256, 0, stream>>>(qkvb, projTb, Sbuf, ssum);
  scan_kernel<<<32, 256, 0, stream>>>(Sbuf, ssum, kvstate, kstate);
  chunk_out_kernel<<<1024, 256, 0, stream>>>(qkvb, projTb, kvstate, kstate, attnb);

  // out GEMM: M=8192, N=1024, K=1024 -> 32x4 = 128 blocks (128%8==0)
  gemm8p_kernel<0,1024><<<128, 512, 0, stream>>>(attnb, woutb, bout, d_out, 1024, 4);
}

// Round 4
// 164.461 us; speedup vs baseline: 1.1660x; 1.1660x over previous
//
#include <hip/hip_runtime.h>
#include <stdint.h>

#define HN 16
#define DH 64
#define MF 64
#define CHK 128
#define NCH 32
#define TSEQ 4096
#define CIN 1024
#define C3 3072

typedef __attribute__((ext_vector_type(8))) short bf16x8;
typedef __attribute__((ext_vector_type(4))) float f32x4;

__device__ __forceinline__ unsigned short f2b(float f){
  union{float f;uint32_t u;} v; v.f=f;
  return (unsigned short)((v.u + 0x7fffu + ((v.u>>16)&1u))>>16);
}

#define MFMA(a,b,c) __builtin_amdgcn_mfma_f32_16x16x32_bf16(a,b,c,0,0,0)

typedef __attribute__((address_space(1))) void gbl_t;
typedef __attribute__((address_space(3))) void lds_t;
__device__ __forceinline__ void gload_lds16(const void* g, void* l){
  __builtin_amdgcn_global_load_lds((const gbl_t*)g, (lds_t*)l, 16, 0, 0);
}

// ---------------- conversion kernels ----------------
__global__ __launch_bounds__(256) void cvt_kernel(const float* __restrict__ src,
                                                  unsigned short* __restrict__ dst, int n4){
  int i = blockIdx.x*256 + threadIdx.x;
  if (i >= n4) return;
  float4 v = ((const float4*)src)[i];
  uint64_t pk = (uint64_t)f2b(v.x) | ((uint64_t)f2b(v.y)<<16)
              | ((uint64_t)f2b(v.z)<<32) | ((uint64_t)f2b(v.w)<<48);
  *(uint64_t*)(dst + (size_t)i*4) = pk;
}

// proj (H,D,M) f32 -> projT (H,M,D) bf16
__global__ __launch_bounds__(256) void projt_kernel(const float* __restrict__ proj,
                                                    unsigned short* __restrict__ projT){
  int i = blockIdx.x*256 + threadIdx.x;
  if (i >= HN*DH*MF) return;
  int h = i>>12, r = i&4095, d = r>>6, m = r&63;
  projT[(h<<12) + (m<<6) + d] = f2b(proj[i]);
}

// ================= 256x128 8-phase GEMM: C[M][N] = A[M][K] * Bt[N][K]^T + bias =================
// 8 waves (2Mx4N), per-wave 128x32 out. BK=64, 2 K-tiles/iteration, 8 phases,
// fragment reuse across phases (phase order (0,0)->(0,1)->(1,1)->(1,0)).
// LDS: sA 2x(256x128B)=64KB (buf<<15), sB 2x(128x128B)=32KB (buf<<14).
// 16B-seg XOR swizzle: seg_stored = seg_true ^ (row&7); global source carries inverse.
// 2 gload issues per phase; counted vmcnt(2) at P4/P8 only.
template<int OUT_BF16, int KK>
__global__ __launch_bounds__(512, 2) void gemm8p_kernel(
    const unsigned short* __restrict__ A, const unsigned short* __restrict__ Bt,
    const float* __restrict__ bias, void* __restrict__ Cout,
    int Nn, int nbN)
{
  static_assert(KK % 128 == 0, "KK multiple of 128");
  constexpr int NT = KK / 64;
  constexpr int NI = NT / 2;
  static_assert((NT & (NT-1)) == 0, "NT pow2 for wrap");

  __shared__ unsigned short sA[2*256*64];
  __shared__ unsigned short sB[2*128*64];

  int tid = threadIdx.x;
  int w = tid>>6, l = tid&63, g = l>>4, r16 = l&15;
  int wr = w>>2, wc = w&3;

  // bijective XCD swizzle (gridDim.x % 8 == 0 at both call sites)
  int nwg = gridDim.x;
  int qq = nwg>>3;
  int wgid = (blockIdx.x & 7)*qq + (blockIdx.x>>3);
  int brow = (wgid / nbN)<<8;
  int bcol = (wgid % nbN)<<7;

  int rofs = tid>>3;                       // row within a 64-row issue
  int cofs = ((tid&7) ^ ((tid>>3)&7))<<3;  // inverse-swizzled source column (elems)

  const unsigned short* Ab = A + (size_t)brow*KK;
  const unsigned short* Bb = Bt + (size_t)bcol*KK;
  char* sAc = (char*)sA;
  char* sBc = (char*)sB;

  f32x4 acc[8][2];
  #pragma unroll
  for (int m=0;m<8;m++)
    #pragma unroll
    for (int n=0;n<2;n++) acc[m][n] = (f32x4){0.f,0.f,0.f,0.f};

  // stage A rows [half*128, half*128+128) of K-tile kt into buf (2 issues)
  auto stgA = [&](int buf, int half, int kt){
    int r0 = half<<7;
    const unsigned short* gp = Ab + (size_t)(r0 + rofs)*KK + (kt<<6) + cofs;
    char* lp = sAc + (buf<<15) + (r0<<7) + (tid<<4);
    gload_lds16(gp, lp);
    gload_lds16(gp + (size_t)64*KK, lp + 8192);
  };
  // stage all 128 B rows of K-tile kt into buf (2 issues)
  auto stgB = [&](int buf, int kt){
    const unsigned short* gp = Bb + (size_t)rofs*KK + (kt<<6) + cofs;
    char* lp = sBc + (buf<<14) + (tid<<4);
    gload_lds16(gp, lp);
    gload_lds16(gp + (size_t)64*KK, lp + 8192);
  };

  bf16x8 af[4][2];     // A frags for current MH half (reused 2 phases)
  bf16x8 bfv[2][2];    // B frags for NH=0 and NH=1 (live across the 4 phases)

#define LDA(SAB, MH) do{                                                            \
    _Pragma("unroll")                                                               \
    for (int mf_=0; mf_<4; mf_++){                                                  \
      int row_ = wr*128 + (MH)*64 + mf_*16 + r16;                                   \
      _Pragma("unroll")                                                             \
      for (int ks_=0; ks_<2; ks_++)                                                 \
        af[mf_][ks_] = *(const bf16x8*)((SAB) + row_*128 + (((ks_*4+g)^(r16&7))<<4));\
    } }while(0)
#define LDB(SBB, NH) do{                                                            \
    int row_ = wc*32 + (NH)*16 + r16;                                               \
    _Pragma("unroll")                                                               \
    for (int ks_=0; ks_<2; ks_++)                                                   \
      bfv[NH][ks_] = *(const bf16x8*)((SBB) + row_*128 + (((ks_*4+g)^(r16&7))<<4)); \
    }while(0)
#define MM(MH, NH) do{                                                              \
    __builtin_amdgcn_s_barrier();                                                   \
    __builtin_amdgcn_sched_barrier(0);                                              \
    __builtin_amdgcn_s_setprio(1);                                                  \
    _Pragma("unroll")                                                               \
    for (int mf_=0; mf_<4; mf_++)                                                   \
      _Pragma("unroll")                                                             \
      for (int ks_=0; ks_<2; ks_++)                                                 \
        acc[(MH)*4+mf_][(NH)] = MFMA(af[mf_][ks_], bfv[NH][ks_], acc[(MH)*4+mf_][(NH)]); \
    __builtin_amdgcn_s_setprio(0);                                                  \
    __builtin_amdgcn_sched_barrier(0);                                              \
    __builtin_amdgcn_s_barrier();                                                   \
    asm volatile("" ::: "memory");                                                  \
  }while(0)
#define VM2 asm volatile("s_waitcnt vmcnt(2)" ::: "memory")

  const char* a0 = sAc;
  const char* a1 = sAc + (1<<15);
  const char* b0 = sBc;
  const char* b1 = sBc + (1<<14);

  // prologue: tile0 full -> buf0 (6 issues), tile1 rows 0-127 -> buf1 (2 issues)
  stgA(0,0,0); stgA(0,1,0); stgB(0,0);
  stgA(1,0,1);
  VM2;                       // drain tile0's 6, leave tile1.A0 in flight
  __builtin_amdgcn_s_barrier();
  asm volatile("" ::: "memory");

  for (int it=0; it<NI; ++it){
    int to  = 2*it+1;
    int tn  = (2*it+2) & (NT-1);
    int tnn = (2*it+3) & (NT-1);
    // even tile in buf0
    LDA(a0,0); LDB(b0,0); stgA(1,1,to);        MM(0,0);   // P1
    LDB(b0,1);            stgB(1,to);          MM(0,1);   // P2
    LDA(a0,1);            stgA(0,0,tn);        MM(1,1);   // P3
                                         VM2;  MM(1,0);   // P4 (odd tile fully staged)
    // odd tile in buf1
    LDA(a1,0); LDB(b1,0); stgA(0,1,tn);        MM(0,0);   // P5
    LDB(b1,1);            stgB(0,tn);          MM(0,1);   // P6
    LDA(a1,1);            stgA(1,0,tnn);       MM(1,1);   // P7
                                         VM2;  MM(1,0);   // P8 (next even tile staged)
  }
#undef LDA
#undef LDB
#undef MM
#undef VM2

  // epilogue
  #pragma unroll
  for (int n=0;n<2;n++){
    int colg = bcol + wc*32 + n*16 + r16;
    float bv = bias[colg];
    #pragma unroll
    for (int m=0;m<8;m++){
      int rowg = brow + wr*128 + (m>>2)*64 + (m&3)*16 + g*4;
      #pragma unroll
      for (int j=0;j<4;j++){
        float v = acc[m][n][j] + bv;
        if (OUT_BF16) ((unsigned short*)Cout)[(size_t)(rowg+j)*Nn + colg] = f2b(v);
        else          ((float*)Cout)[(size_t)(rowg+j)*Nn + colg] = v;
      }
    }
  }
}

// ---------------- per-chunk stats: S = kp^T v, ssum = sum_t kp ----------------
__global__ __launch_bounds__(256) void chunk_stats_kernel(
    const unsigned short* __restrict__ qkvb,
    const unsigned short* __restrict__ projT,
    float* __restrict__ Sbuf, float* __restrict__ ssum)
{
  __shared__ unsigned short s_pT[64*64];    // [m][d]  rows 128B, swz (m&7)<<4
  __shared__ unsigned short s_kpT[64*128];  // [m][t]  rows 256B, swz (m&15)<<4
  __shared__ unsigned short s_vT[64*128];   // [d][t]  rows 256B, swz (d&15)<<4
  __shared__ float s_part[256];

  int bid = blockIdx.x;
  int ch = bid&31, h = (bid>>5)&15, b = bid>>9;
  int tid = threadIdx.x, w = tid>>6, l = tid&63, g = l>>4, r16 = l&15;
  int rowbase = b*TSEQ + ch*CHK;
  const unsigned short* kg = qkvb + (size_t)rowbase*C3 + CIN   + h*DH;
  const unsigned short* vg = qkvb + (size_t)rowbase*C3 + 2*CIN + h*DH;

  {
    const unsigned short* p = projT + (h<<12);
    for (int i = tid; i < 4096; i += 256){
      int m = i>>6, d = i&63;
      *(unsigned short*)((char*)s_pT + m*128 + (((d*2) ^ ((m&7)<<4)))) = p[i];
    }
  }
  for (int i = tid; i < 1024; i += 256){
    int t = i>>3, d0 = (i&7)<<3;
    bf16x8 vv = *(const bf16x8*)(vg + (size_t)t*C3 + d0);
    #pragma unroll
    for (int j=0;j<8;j++){
      int d = d0+j;
      *(unsigned short*)((char*)s_vT + d*256 + (((t*2) ^ ((d&15)<<4)))) = (unsigned short)vv[j];
    }
  }
  __syncthreads();

  // kp = relu(k @ projT^T): M=t(128 rows, 32/wave), N=m(64), K=d(64)
  f32x4 kacc[2][4];
  #pragma unroll
  for (int tr=0;tr<2;tr++)
    #pragma unroll
    for (int nc=0;nc<4;nc++) kacc[tr][nc] = (f32x4){0.f,0.f,0.f,0.f};
  #pragma unroll
  for (int ks=0; ks<2; ks++){
    bf16x8 a[2];
    #pragma unroll
    for (int tr=0;tr<2;tr++){
      int t = w*32 + tr*16 + r16;
      a[tr] = *(const bf16x8*)(kg + (size_t)t*C3 + ks*32 + g*8);
    }
    #pragma unroll
    for (int nc=0;nc<4;nc++){
      int m = nc*16 + r16;
      bf16x8 bb = *(const bf16x8*)((const char*)s_pT + m*128 + (((ks*64 + g*16) ^ ((m&7)<<4))));
      #pragma unroll
      for (int tr=0;tr<2;tr++)
        kacc[tr][nc] = MFMA(a[tr], bb, kacc[tr][nc]);
    }
  }
  #pragma unroll
  for (int nc=0;nc<4;nc++){
    float v = 0.f;
    #pragma unroll
    for (int tr=0;tr<2;tr++)
      #pragma unroll
      for (int j=0;j<4;j++){
        float x = kacc[tr][nc][j]; x = x>0.f?x:0.f;
        v += x;
        int t = w*32 + tr*16 + g*4 + j;
        int m = nc*16 + r16;
        *(unsigned short*)((char*)s_kpT + m*256 + (((t*2) ^ ((m&15)<<4)))) = f2b(x);
      }
    v += __shfl_xor(v,16); v += __shfl_xor(v,32);
    if (g==0) s_part[w*64 + nc*16 + r16] = v;
  }
  __syncthreads();

  // S[m][d] = sum_t kp[t][m] v[t][d]: A=s_kpT [m][t], B=s_vT [d][t], K=t(128)
  f32x4 sacc[4];
  #pragma unroll
  for (int dc=0;dc<4;dc++) sacc[dc] = (f32x4){0.f,0.f,0.f,0.f};
  int mrow = w*16 + r16;
  #pragma unroll
  for (int ks=0; ks<4; ks++){
    bf16x8 a = *(const bf16x8*)((const char*)s_kpT + mrow*256 + (((ks*64 + g*16) ^ ((mrow&15)<<4))));
    #pragma unroll
    for (int dc=0; dc<4; dc++){
      int d = dc*16 + r16;
      bf16x8 bb = *(const bf16x8*)((const char*)s_vT + d*256 + (((ks*64 + g*16) ^ ((d&15)<<4))));
      sacc[dc] = MFMA(a, bb, sacc[dc]);
    }
  }
  float* So = Sbuf + ((size_t)((b*HN + h)*NCH + ch))*4096;
  #pragma unroll
  for (int dc=0; dc<4; dc++)
    #pragma unroll
    for (int j=0;j<4;j++)
      So[(w*16 + g*4 + j)*64 + dc*16 + r16] = sacc[dc][j];
  if (tid < 64){
    float v = s_part[tid] + s_part[64+tid] + s_part[128+tid] + s_part[192+tid];
    ssum[((size_t)((b*HN + h)*NCH + ch))*64 + tid] = v;
  }
}

// ---------------- exclusive prefix over chunks (4-way D-split) ----------------
__global__ __launch_bounds__(256) void scan_kernel(
  const float* __restrict__ Sbuf, const float* __restrict__ ssum,
  float* __restrict__ kvstate, float* __restrict__ kstate)
{
  int bh = blockIdx.x>>2, qd = blockIdx.x&3, tid = threadIdx.x;
  const float4* Sp = (const float4*)(Sbuf + (size_t)bh*NCH*4096);
  float4* kvp = (float4*)(kvstate + (size_t)bh*NCH*4096);
  int idx0 = (tid>>2)*16 + qd*4 + (tid&3);   // within-chunk float4 index
  float4 acc = make_float4(0.f,0.f,0.f,0.f);
  for (int c2=0; c2<NCH; c2++){
    int idx = c2*1024 + idx0;
    float4 s = Sp[idx];
    kvp[idx] = acc;
    acc.x += s.x; acc.y += s.y; acc.z += s.z; acc.w += s.w;
  }
  if (qd==0 && tid < 64){
    float a = 0.f;
    const float* sp = ssum + (size_t)bh*NCH*64;
    float* kp2 = kstate + (size_t)bh*NCH*64;
    for (int c2=0;c2<NCH;c2++){ kp2[c2*64+tid] = a; a += sp[c2*64+tid]; }
  }
}

// ---------------- per-chunk output ----------------
__global__ __launch_bounds__(256) void chunk_out_kernel(
    const unsigned short* __restrict__ qkvb,
    const unsigned short* __restrict__ projT,
    const float* __restrict__ kvstate,
    const float* __restrict__ kstate,
    unsigned short* __restrict__ attnb)
{
  __shared__ unsigned short s_qp[128*64];   // [t][m] rows 128B, swz (t&7)<<4
  __shared__ unsigned short s_kp[128*64];   // [s][m] rows 128B, swz (s&7)<<4
  __shared__ unsigned short s_vT[64*128];   // [d][t] rows 256B, swz (d&15)<<4
  __shared__ unsigned short s_pa[64*64];    // projT [m][d] swz (m&7)<<4, then aw_sb [t][32] swz (t&3)<<4

  int bid = blockIdx.x;
  int ch = bid&31, h=(bid>>5)&15, b=bid>>9;
  int tid=threadIdx.x, w=tid>>6, l=tid&63, g=l>>4, r16=l&15;
  int rowbase = b*TSEQ + ch*CHK;
  const unsigned short* qg = qkvb + (size_t)rowbase*C3 + h*DH;
  const unsigned short* kg = qg + CIN;
  const unsigned short* vg = qg + 2*CIN;
  const float* kvg = kvstate + ((size_t)((b*HN+h)*NCH + ch))*4096;
  const float* ksg = kstate  + ((size_t)((b*HN+h)*NCH + ch))*64;

  {
    const unsigned short* p = projT + (h<<12);
    for (int i = tid; i < 4096; i += 256){
      int m = i>>6, d = i&63;
      *(unsigned short*)((char*)s_pa + m*128 + (((d*2) ^ ((m&7)<<4)))) = p[i];
    }
  }
  for (int i = tid; i < 1024; i += 256){
    int t = i>>3, d0 = (i&7)<<3;
    bf16x8 vv = *(const bf16x8*)(vg + (size_t)t*C3 + d0);
    #pragma unroll
    for (int j=0;j<8;j++){
      int d = d0+j;
      *(unsigned short*)((char*)s_vT + d*256 + (((t*2) ^ ((d&15)<<4)))) = (unsigned short)vv[j];
    }
  }
  __syncthreads();

  // qp = relu(q @ projT^T)
  f32x4 qacc[2][4];
  #pragma unroll
  for (int tr=0;tr<2;tr++)
    #pragma unroll
    for (int nc=0;nc<4;nc++) qacc[tr][nc] = (f32x4){0.f,0.f,0.f,0.f};
  #pragma unroll
  for (int ks=0; ks<2; ks++){
    bf16x8 a[2];
    #pragma unroll
    for (int tr=0;tr<2;tr++){
      int t = w*32 + tr*16 + r16;
      a[tr] = *(const bf16x8*)(qg + (size_t)t*C3 + ks*32 + g*8);
    }
    #pragma unroll
    for (int nc=0;nc<4;nc++){
      int m = nc*16 + r16;
      bf16x8 bb = *(const bf16x8*)((const char*)s_pa + m*128 + (((ks*64 + g*16) ^ ((m&7)<<4))));
      #pragma unroll
      for (int tr=0;tr<2;tr++)
        qacc[tr][nc] = MFMA(a[tr], bb, qacc[tr][nc]);
    }
  }
  // norm_hist partials + write qp
  float nh[2][4];
  #pragma unroll
  for (int tr=0;tr<2;tr++)
    #pragma unroll
    for (int j=0;j<4;j++) nh[tr][j] = 0.f;
  #pragma unroll
  for (int nc=0;nc<4;nc++){
    float ksv = ksg[nc*16 + r16];
    #pragma unroll
    for (int tr=0;tr<2;tr++)
      #pragma unroll
      for (int j=0;j<4;j++){
        float x = qacc[tr][nc][j]; x = x>0.f?x:0.f;
        nh[tr][j] += x*ksv;
        int t = w*32 + tr*16 + g*4 + j;
        int m = nc*16 + r16;
        *(unsigned short*)((char*)s_qp + t*128 + (((m*2) ^ ((t&7)<<4)))) = f2b(x);
      }
  }
  // kp = relu(k @ projT^T)
  f32x4 kacc[2][4];
  #pragma unroll
  for (int tr=0;tr<2;tr++)
    #pragma unroll
    for (int nc=0;nc<4;nc++) kacc[tr][nc] = (f32x4){0.f,0.f,0.f,0.f};
  #pragma unroll
  for (int ks=0; ks<2; ks++){
    bf16x8 a[2];
    #pragma unroll
    for (int tr=0;tr<2;tr++){
      int t = w*32 + tr*16 + r16;
      a[tr] = *(const bf16x8*)(kg + (size_t)t*C3 + ks*32 + g*8);
    }
    #pragma unroll
    for (int nc=0;nc<4;nc++){
      int m = nc*16 + r16;
      bf16x8 bb = *(const bf16x8*)((const char*)s_pa + m*128 + (((ks*64 + g*16) ^ ((m&7)<<4))));
      #pragma unroll
      for (int tr=0;tr<2;tr++)
        kacc[tr][nc] = MFMA(a[tr], bb, kacc[tr][nc]);
    }
  }
  #pragma unroll
  for (int nc=0;nc<4;nc++)
    #pragma unroll
    for (int tr=0;tr<2;tr++)
      #pragma unroll
      for (int j=0;j<4;j++){
        float x = kacc[tr][nc][j]; x = x>0.f?x:0.f;
        int t = w*32 + tr*16 + g*4 + j;
        int m = nc*16 + r16;
        *(unsigned short*)((char*)s_kp + t*128 + (((m*2) ^ ((t&7)<<4)))) = f2b(x);
      }
  __syncthreads();   // qp/kp ready; projT no longer needed

  f32x4 ctx[2][4];
  float ni[2][4];
  #pragma unroll
  for (int tr=0;tr<2;tr++){
    #pragma unroll
    for (int dc=0;dc<4;dc++) ctx[tr][dc] = (f32x4){0.f,0.f,0.f,0.f};
    #pragma unroll
    for (int j=0;j<4;j++) ni[tr][j] = 0.f;
  }

  // streamed aw (128x32 per block) + ctx_intra
  for (int sb=0; sb<4; sb++){
    f32x4 aw[2][2];
    #pragma unroll
    for (int tr=0;tr<2;tr++)
      #pragma unroll
      for (int sc=0;sc<2;sc++) aw[tr][sc] = (f32x4){0.f,0.f,0.f,0.f};
    #pragma unroll
    for (int ks=0; ks<2; ks++){
      bf16x8 a[2];
      #pragma unroll
      for (int tr=0;tr<2;tr++){
        int t = w*32 + tr*16 + r16;
        a[tr] = *(const bf16x8*)((const char*)s_qp + t*128 + (((ks*64 + g*16) ^ ((t&7)<<4))));
      }
      #pragma unroll
      for (int sc=0;sc<2;sc++){
        int s = sb*32 + sc*16 + r16;
        bf16x8 bb = *(const bf16x8*)((const char*)s_kp + s*128 + (((ks*64 + g*16) ^ ((s&7)<<4))));
        #pragma unroll
        for (int tr=0;tr<2;tr++)
          aw[tr][sc] = MFMA(a[tr], bb, aw[tr][sc]);
      }
    }
    #pragma unroll
    for (int tr=0;tr<2;tr++)
      #pragma unroll
      for (int sc=0;sc<2;sc++)
        #pragma unroll
        for (int j=0;j<4;j++){
          int t = w*32 + tr*16 + g*4 + j;
          int s = sb*32 + sc*16 + r16;
          float x = (s<=t)? aw[tr][sc][j] : 0.f;
          ni[tr][j] += x;
          int sl = sc*16 + r16;
          *(unsigned short*)((char*)s_pa + t*64 + (((sl*2) ^ ((t&3)<<4)))) = f2b(x);
        }
    __syncthreads();
    #pragma unroll
    for (int tr=0;tr<2;tr++){
      int t = w*32 + tr*16 + r16;
      bf16x8 a2 = *(const bf16x8*)((const char*)s_pa + t*64 + (((g*16) ^ ((t&3)<<4))));
      #pragma unroll
      for (int dc=0;dc<4;dc++){
        int d = dc*16 + r16;
        bf16x8 bb = *(const bf16x8*)((const char*)s_vT + d*256 + (((sb*64 + g*16) ^ ((d&15)<<4))));
        ctx[tr][dc] = MFMA(a2, bb, ctx[tr][dc]);
      }
    }
    __syncthreads();
  }

  // ctx_hist += qp @ kv_state  (B[k=m][n=d] = kvstate[m][d], scalar f32 loads)
  #pragma unroll
  for (int ks=0; ks<2; ks++){
    bf16x8 a[2];
    #pragma unroll
    for (int tr=0;tr<2;tr++){
      int t = w*32 + tr*16 + r16;
      a[tr] = *(const bf16x8*)((const char*)s_qp + t*128 + (((ks*64 + g*16) ^ ((t&7)<<4))));
    }
    #pragma unroll
    for (int dc=0;dc<4;dc++){
      bf16x8 bb;
      #pragma unroll
      for (int i=0;i<8;i++)
        bb[i] = (short)f2b(kvg[(ks*32 + g*8 + i)*64 + dc*16 + r16]);
      #pragma unroll
      for (int tr=0;tr<2;tr++)
        ctx[tr][dc] = MFMA(a[tr], bb, ctx[tr][dc]);
    }
  }

  // norms: butterfly over the 16-lane group (sums s-mod-16 / m-mod-16 partials)
  float nrm[2][4];
  #pragma unroll
  for (int tr=0;tr<2;tr++)
    #pragma unroll
    for (int j=0;j<4;j++){
      float v = nh[tr][j] + ni[tr][j];
      v += __shfl_xor(v,1); v += __shfl_xor(v,2);
      v += __shfl_xor(v,4); v += __shfl_xor(v,8);
      nrm[tr][j] = v + 1e-6f;
    }

  #pragma unroll
  for (int tr=0;tr<2;tr++)
    #pragma unroll
    for (int dc=0;dc<4;dc++)
      #pragma unroll
      for (int j=0;j<4;j++){
        int t = w*32 + tr*16 + g*4 + j;
        int d = dc*16 + r16;
        attnb[(size_t)(rowbase + t)*CIN + h*DH + d] = f2b(ctx[tr][dc][j] / nrm[tr][j]);
      }
}

// ---------------- launch ----------------
extern "C" void kernel_launch(void* const* d_in, const int* in_sizes, int n_in,
                              void* d_out, int out_size, void* d_ws, size_t ws_size,
                              hipStream_t stream)
{
  const float* x    = (const float*)d_in[0];
  const float* Wqkv = (const float*)d_in[1];
  const float* bqkv = (const float*)d_in[2];
  const float* Wout = (const float*)d_in[3];
  const float* bout = (const float*)d_in[4];
  const float* proj = (const float*)d_in[5];

  char* ws = (char*)d_ws;
  unsigned short* xb     = (unsigned short*)(ws + 0);         // 16 MB (reused as attnb)
  unsigned short* attnb  = (unsigned short*)(ws + 0);
  unsigned short* wqkvb  = (unsigned short*)(ws + 16777216);  // 6 MB (reused as ssum/kstate)
  float*          ssum   = (float*)(ws + 16777216);
  float*          kstate = (float*)(ws + 17039360);
  unsigned short* qkvb   = (unsigned short*)(ws + 23068672);  // 50 MB
  unsigned short* woutb  = (unsigned short*)(ws + 73400320);  // 2 MB
  unsigned short* projTb = (unsigned short*)(ws + 75497472);  // 128 KB
  float*          Sbuf   = (float*)(ws + 75628544);           // 16 MB
  float*          kvstate= (float*)(ws + 92405760);           // 16 MB

  cvt_kernel<<<8192, 256, 0, stream>>>(x, xb, 2097152);
  cvt_kernel<<<3072, 256, 0, stream>>>(Wqkv, wqkvb, 786432);
  cvt_kernel<<<1024, 256, 0, stream>>>(Wout, woutb, 262144);
  projt_kernel<<<256, 256, 0, stream>>>(proj, projTb);

  // QKV GEMM: M=8192, N=3072 -> 32x24 = 768 blocks (3.0 exact rounds)
  gemm8p_kernel<1,1024><<<768, 512, 0, stream>>>(xb, wqkvb, bqkv, qkvb, 3072, 24);

  chunk_stats_kernel<<<1024, 256, 0, stream>>>(qkvb, projTb, Sbuf, ssum);
  scan_kernel<<<128, 256, 0, stream>>>(Sbuf, ssum, kvstate, kstate);
  chunk_out_kernel<<<1024, 256, 0, stream>>>(qkvb, projTb, kvstate, kstate, attnb);

  // out GEMM: M=8192, N=1024 -> 32x8 = 256 blocks (1.0 exact round)
  gemm8p_kernel<0,1024><<<256, 512, 0, stream>>>(attnb, woutb, bout, d_out, 1024, 8);
}